// Round 1
// baseline (506.033 us; speedup 1.0000x reference)
//
#include <hip/hip_runtime.h>
#include <cmath>

#define H 128
#define EPS 1e-5f

typedef __attribute__((ext_vector_type(8))) __bf16 bf16x8;
typedef __attribute__((ext_vector_type(4))) float f32x4;
typedef __attribute__((ext_vector_type(4))) unsigned short u16x4;
typedef __attribute__((ext_vector_type(8))) unsigned short u16x8;

__device__ __forceinline__ float gelu_exact(float x) {
    return 0.5f * x * (1.0f + erff(x * 0.70710678118654752f));
}

__device__ __forceinline__ unsigned short f2bfu(float f) {
    __bf16 h = (__bf16)f;   // RNE fptrunc
    return __builtin_bit_cast(unsigned short, h);
}

// ---------------------------------------------------------------------------
// K1: fused edge kernel.
// pos_e = x[src] + edge_attr ; v = gelu(pos_e @ W1^T + b1) * bases ;
// atomicAdd into aggr[dst].
// Block = 256 threads (4 waves). Tile = 64 edges x 128 cols. K = 128.
// Wave w owns output cols [w*32, w*32+32) (2 MFMA n-tiles).
// W1 fragments preloaded to registers once per block.
// ---------------------------------------------------------------------------
__global__ __launch_bounds__(256) void edge_kernel(
    const float* __restrict__ x, const float* __restrict__ ea,
    const float* __restrict__ bases, const int* __restrict__ src,
    const int* __restrict__ dst, const float* __restrict__ W1,
    const float* __restrict__ b1, float* __restrict__ aggr,
    int E, int ntiles)
{
    __shared__ __align__(16) unsigned short alds[64 * 128];

    const int tid = threadIdx.x;
    const int w = tid >> 6, l = tid & 63, lg = l >> 4, lr = l & 15;
    const int er = tid >> 2, q = tid & 3;

    // Preload B fragments (W1) and bias. B[k][n] = W1[n][k].
    bf16x8 bf[2][4];
    float b1v[2];
#pragma unroll
    for (int n = 0; n < 2; ++n) {
        int row = w * 32 + n * 16 + lr;
        b1v[n] = b1[row];
#pragma unroll
        for (int kk = 0; kk < 4; ++kk) {
            const float* p = W1 + row * H + kk * 32 + lg * 8;
            u16x8 t;
#pragma unroll
            for (int i = 0; i < 8; ++i) t[i] = f2bfu(p[i]);
            bf[n][kk] = __builtin_bit_cast(bf16x8, t);
        }
    }

    for (int t = blockIdx.x; t < ntiles; t += gridDim.x) {
        const int e0 = t * 64;
        // ---- stage pos_e tile (64 x 128) as bf16, XOR-swizzled ----
        {
            int e = e0 + er;
            int ec = e < E ? e : E - 1;
            int s = src[ec];
            const f32x4* pe = reinterpret_cast<const f32x4*>(ea + (long)ec * H + q * 32);
            const f32x4* px = reinterpret_cast<const f32x4*>(x + (long)s * H + q * 32);
            const int swz = (er & 7) << 3;
#pragma unroll
            for (int i = 0; i < 8; ++i) {
                f32x4 a = pe[i];
                f32x4 b = px[i];
                u16x4 o;
                o[0] = f2bfu(a[0] + b[0]);
                o[1] = f2bfu(a[1] + b[1]);
                o[2] = f2bfu(a[2] + b[2]);
                o[3] = f2bfu(a[3] + b[3]);
                int col = q * 32 + i * 4;
                *reinterpret_cast<u16x4*>(&alds[er * 128 + (col ^ swz)]) = o;
            }
        }
        __syncthreads();

        // ---- compute + epilogue ----
#pragma unroll
        for (int m = 0; m < 4; ++m) {
            const int arow = m * 16 + lr;
            const int aswz = (arow & 7) << 3;
            bf16x8 af[4];
#pragma unroll
            for (int kk = 0; kk < 4; ++kk)
                af[kk] = __builtin_bit_cast(bf16x8,
                    *reinterpret_cast<const u16x8*>(&alds[arow * 128 + ((kk * 32 + lg * 8) ^ aswz)]));
#pragma unroll
            for (int n = 0; n < 2; ++n) {
                f32x4 acc = {0.f, 0.f, 0.f, 0.f};
#pragma unroll
                for (int kk = 0; kk < 4; ++kk)
                    acc = __builtin_amdgcn_mfma_f32_16x16x32_bf16(af[kk], bf[n][kk], acc, 0, 0, 0);
                const int j = w * 32 + n * 16 + lr;
#pragma unroll
                for (int r = 0; r < 4; ++r) {
                    int e = e0 + m * 16 + lg * 4 + r;
                    if (e < E) {
                        float z = acc[r] + b1v[n];
                        float v = gelu_exact(z) * bases[(long)e * H + j];
                        atomicAdd(&aggr[(long)dst[e] * H + j], v);
                    }
                }
            }
        }
        __syncthreads();
    }
}

// ---------------------------------------------------------------------------
// K2/K4: node GEMM  Y = f(A) @ W^T + bias, with fused column sum/sumsq
// epilogue for BatchNorm stats. PRE=true applies gelu(a*scale+shift) on load.
// Grid = N/64 blocks, one 64-row tile per block.
// ---------------------------------------------------------------------------
template <bool PRE>
__global__ __launch_bounds__(256) void node_gemm(
    const float* __restrict__ A, const float* __restrict__ W,
    const float* __restrict__ bias, const float* __restrict__ scl,
    const float* __restrict__ shf, float* __restrict__ Y,
    float* __restrict__ csum, float* __restrict__ cssq, int Nn)
{
    __shared__ __align__(16) unsigned short alds[64 * 128];

    const int tid = threadIdx.x;
    const int w = tid >> 6, l = tid & 63, lg = l >> 4, lr = l & 15;
    const int er = tid >> 2, q = tid & 3;
    const int r0 = blockIdx.x * 64;

    bf16x8 bf[2][4];
    float bv[2];
#pragma unroll
    for (int n = 0; n < 2; ++n) {
        int row = w * 32 + n * 16 + lr;
        bv[n] = bias[row];
#pragma unroll
        for (int kk = 0; kk < 4; ++kk) {
            const float* p = W + row * H + kk * 32 + lg * 8;
            u16x8 t;
#pragma unroll
            for (int i = 0; i < 8; ++i) t[i] = f2bfu(p[i]);
            bf[n][kk] = __builtin_bit_cast(bf16x8, t);
        }
    }

    // ---- stage A tile ----
    {
        int rr = r0 + er;
        int rc = rr < Nn ? rr : Nn - 1;
        const f32x4* pa = reinterpret_cast<const f32x4*>(A + (long)rc * H + q * 32);
        const int swz = (er & 7) << 3;
#pragma unroll
        for (int i = 0; i < 8; ++i) {
            f32x4 v = pa[i];
            if constexpr (PRE) {
                f32x4 sc = *reinterpret_cast<const f32x4*>(scl + q * 32 + i * 4);
                f32x4 sh = *reinterpret_cast<const f32x4*>(shf + q * 32 + i * 4);
#pragma unroll
                for (int c = 0; c < 4; ++c) v[c] = gelu_exact(v[c] * sc[c] + sh[c]);
            }
            u16x4 o;
            o[0] = f2bfu(v[0]);
            o[1] = f2bfu(v[1]);
            o[2] = f2bfu(v[2]);
            o[3] = f2bfu(v[3]);
            int col = q * 32 + i * 4;
            *reinterpret_cast<u16x4*>(&alds[er * 128 + (col ^ swz)]) = o;
        }
    }
    __syncthreads();

    float ps[2] = {0.f, 0.f}, ps2[2] = {0.f, 0.f};
#pragma unroll
    for (int m = 0; m < 4; ++m) {
        const int arow = m * 16 + lr;
        const int aswz = (arow & 7) << 3;
        bf16x8 af[4];
#pragma unroll
        for (int kk = 0; kk < 4; ++kk)
            af[kk] = __builtin_bit_cast(bf16x8,
                *reinterpret_cast<const u16x8*>(&alds[arow * 128 + ((kk * 32 + lg * 8) ^ aswz)]));
#pragma unroll
        for (int n = 0; n < 2; ++n) {
            f32x4 acc = {0.f, 0.f, 0.f, 0.f};
#pragma unroll
            for (int kk = 0; kk < 4; ++kk)
                acc = __builtin_amdgcn_mfma_f32_16x16x32_bf16(af[kk], bf[n][kk], acc, 0, 0, 0);
            const int j = w * 32 + n * 16 + lr;
#pragma unroll
            for (int r = 0; r < 4; ++r) {
                int rr = r0 + m * 16 + lg * 4 + r;
                if (rr < Nn) {
                    float z = acc[r] + bv[n];
                    Y[(long)rr * H + j] = z;
                    ps[n] += z;
                    ps2[n] += z * z;
                }
            }
        }
    }
    // ---- column stats reduction (over the 4 lane-groups) ----
#pragma unroll
    for (int n = 0; n < 2; ++n) {
        float s = ps[n];
        s += __shfl_xor(s, 16);
        s += __shfl_xor(s, 32);
        float s2 = ps2[n];
        s2 += __shfl_xor(s2, 16);
        s2 += __shfl_xor(s2, 32);
        if (lg == 0) {
            int j = w * 32 + n * 16 + lr;
            atomicAdd(&csum[j], s);
            atomicAdd(&cssq[j], s2);
        }
    }
}

// ---------------------------------------------------------------------------
// BN finalize: scale = g * rsqrt(var + eps), shift = beta - mu * scale
// ---------------------------------------------------------------------------
__global__ void finalize_bn(const float* __restrict__ csum, const float* __restrict__ cssq,
                            const float* __restrict__ g, const float* __restrict__ be,
                            float* __restrict__ scl, float* __restrict__ shf, float invN)
{
    int j = threadIdx.x;
    float mu = csum[j] * invN;
    float var = fmaxf(cssq[j] * invN - mu * mu, 0.f);
    float s = g[j] * rsqrtf(var + EPS);
    scl[j] = s;
    shf[j] = be[j] - mu * s;
}

// ---------------------------------------------------------------------------
// K6: out = gelu(y2 * scale2 + shift2), vectorized float4
// ---------------------------------------------------------------------------
__global__ __launch_bounds__(256) void final_gelu(
    const float* __restrict__ Y2, const float* __restrict__ scl,
    const float* __restrict__ shf, float* __restrict__ out, long n4)
{
    long i = (long)blockIdx.x * blockDim.x + threadIdx.x;
    const long stride = (long)gridDim.x * blockDim.x;
    for (; i < n4; i += stride) {
        f32x4 v = reinterpret_cast<const f32x4*>(Y2)[i];
        int c4 = (int)(i & 31);
        f32x4 sc = reinterpret_cast<const f32x4*>(scl)[c4];
        f32x4 sh = reinterpret_cast<const f32x4*>(shf)[c4];
        f32x4 o;
#pragma unroll
        for (int c = 0; c < 4; ++c) o[c] = gelu_exact(v[c] * sc[c] + sh[c]);
        reinterpret_cast<f32x4*>(out)[i] = o;
    }
}

extern "C" void kernel_launch(void* const* d_in, const int* in_sizes, int n_in,
                              void* d_out, int out_size, void* d_ws, size_t ws_size,
                              hipStream_t stream) {
    const float* x     = (const float*)d_in[0];
    const float* ea    = (const float*)d_in[1];
    const float* bases = (const float*)d_in[2];
    const int*   src   = (const int*)d_in[3];
    const int*   dst   = (const int*)d_in[4];
    const float* W1    = (const float*)d_in[5];
    const float* b1    = (const float*)d_in[6];
    const float* W2    = (const float*)d_in[7];
    const float* b2    = (const float*)d_in[8];
    const float* g1    = (const float*)d_in[9];
    const float* be1   = (const float*)d_in[10];
    const float* W3    = (const float*)d_in[11];
    const float* b3    = (const float*)d_in[12];
    const float* g2    = (const float*)d_in[13];
    const float* be2   = (const float*)d_in[14];

    const int N = in_sizes[0] / H;
    const int E = in_sizes[1] / H;

    float* ws    = (float*)d_ws;
    float* aggr  = ws;                        // [N,H]; reused as y2 by K4
    float* y1    = ws + (size_t)N * H;        // [N,H]
    float* stats = ws + (size_t)2 * N * H;    // 1024 floats
    float* sum1 = stats,        *ss1 = stats + 128;
    float* sum2 = stats + 256,  *ss2 = stats + 384;
    float* scl1 = stats + 512,  *shf1 = stats + 640;
    float* scl2 = stats + 768,  *shf2 = stats + 896;

    hipMemsetAsync(aggr, 0, (size_t)N * H * sizeof(float), stream);
    hipMemsetAsync(stats, 0, 512 * sizeof(float), stream);

    const int ntiles = (E + 63) / 64;
    edge_kernel<<<2500, 256, 0, stream>>>(x, ea, bases, src, dst, W1, b1, aggr, E, ntiles);

    const int nblk = (N + 63) / 64;
    node_gemm<false><<<nblk, 256, 0, stream>>>(aggr, W2, b2, nullptr, nullptr, y1, sum1, ss1, N);
    finalize_bn<<<1, 128, 0, stream>>>(sum1, ss1, g1, be1, scl1, shf1, 1.0f / (float)N);
    node_gemm<true><<<nblk, 256, 0, stream>>>(y1, W3, b3, scl1, shf1, aggr, sum2, ss2, N);
    finalize_bn<<<1, 128, 0, stream>>>(sum2, ss2, g2, be2, scl2, shf2, 1.0f / (float)N);

    long n4 = (long)N * H / 4;
    final_gelu<<<2048, 256, 0, stream>>>(aggr, scl2, shf2, (float*)d_out, n4);
}